// Round 1
// baseline (235.917 us; speedup 1.0000x reference)
//
#include <hip/hip_runtime.h>
#include <math.h>
#include <stdint.h>

#define NTOK  16384
#define NW6   (NTOK * 6)
#define D4    512              // float4 per full 2048-dim row
#define WF4   2304             // 18 rows x 128 float4 per D-segment (36,864 B)
#define XB    512              // 32 tokens x 16 float4 per x chunk buffer (8,192 B)
#define NCC   32               // 64-dim chunks across full D (4 seg x 8)

#define DOT4(a, b) ((a).x*(b).x + (a).y*(b).y + (a).z*(b).z + (a).w*(b).w)

// Async global->LDS DMA, 16 B per lane. LDS dest = wave-uniform base +
// lane*16 (contiguous); global src is per-lane. No destination VGPRs.
#define ASYNC_CP16(gsrc, ldst)                                              \
    __builtin_amdgcn_global_load_lds(                                       \
        (const __attribute__((address_space(1))) void*)(gsrc),              \
        (__attribute__((address_space(3))) void*)(ldst), 16, 0, 0)

// DPP row_shl sum-tree: lane i adds lane i+N (out-of-range -> 0). After 4
// steps lane 0 of each 16-lane row holds the full row sum. (Verified.)
template <int CTRL>
__device__ __forceinline__ float dpp_add(float v) {
    int moved = __builtin_amdgcn_update_dpp(0, __float_as_int(v),
                                            CTRL, 0xF, 0xF, true);
    return v + __int_as_float(moved);
}
__device__ __forceinline__ float row_reduce16(float v) {
    v = dpp_add<0x108>(v);   // row_shl:8
    v = dpp_add<0x104>(v);   // row_shl:4
    v = dpp_add<0x102>(v);   // row_shl:2
    v = dpp_add<0x101>(v);   // row_shl:1
    return v;
}

// Routing math for one token given its 18 full scores (proven in the
// two-phase version; math identical to reference `_router`).
__device__ __forceinline__ void route_one(const float* __restrict__ s,
                                          int tok,
                                          float* __restrict__ out,
                                          unsigned int* __restrict__ lcnt)
{
    const float g0 = 1.f / (1.f + expf(-s[16]));
    const float g1 = 1.f / (1.f + expf(-s[17]));

    // --- Group A: experts 0..7, top-1 of softmax ---
    int aidx = 0; float amax = s[0];
#pragma unroll
    for (int i = 1; i < 8; ++i)
        if (s[i] > amax) { amax = s[i]; aidx = i; }
    float asum = 0.f;
#pragma unroll
    for (int i = 0; i < 8; ++i) asum += expf(s[i] - amax);
    const float a_best = 1.f / asum;

    // --- Group B: experts 8..11, top-1, gated by g0 ---
    int bidx = 0; float bmax = s[8];
#pragma unroll
    for (int i = 1; i < 4; ++i)
        if (s[8 + i] > bmax) { bmax = s[8 + i]; bidx = i; }
    float bsum = 0.f;
#pragma unroll
    for (int i = 0; i < 4; ++i) bsum += expf(s[8 + i] - bmax);
    const float b_w = (g0 > 0.15f) ? ((1.f / bsum) * g0) : 0.f;

    // --- Group C: experts 12..15, top-2 of softmax, gated by g1 ---
    int c1 = 0; float cmax = s[12];
#pragma unroll
    for (int i = 1; i < 4; ++i)
        if (s[12 + i] > cmax) { cmax = s[12 + i]; c1 = i; }
    float csum = 0.f;
#pragma unroll
    for (int i = 0; i < 4; ++i) csum += expf(s[12 + i] - cmax);
    int c2 = -1; float c2v = -1e30f;
#pragma unroll
    for (int i = 0; i < 4; ++i)
        if (i != c1 && s[12 + i] > c2v) { c2v = s[12 + i]; c2 = i; }
    const float cg   = (g1 > 0.15f) ? g1 : 0.f;
    const float c_w1 = (1.f / csum) * cg;
    const float c_w2 = (expf(c2v - cmax) / csum) * cg;

    // --- normalize and write ---
    const float inv = 1.f / (a_best + b_w + c_w1 + c_w2 + 1e-8f);
    float2* ow = reinterpret_cast<float2*>(out + (size_t)tok * 6);
    ow[0] = make_float2(a_best * inv, b_w * inv);
    ow[1] = make_float2(c_w1 * inv, c_w2 * inv);
    ow[2] = make_float2(0.f, 0.f);
    float2* oi = reinterpret_cast<float2*>(out + NW6 + (size_t)tok * 6);
    oi[0] = make_float2((float)aidx, (float)(8 + bidx));
    oi[1] = make_float2((float)(12 + c1), (float)(12 + c2));
    oi[2] = make_float2(0.f, 0.f);

    atomicAdd(&lcnt[aidx], 1u);
    atomicAdd(&lcnt[8 + bidx], 1u);
    atomicAdd(&lcnt[12 + c1], 1u);
    atomicAdd(&lcnt[12 + c2], 1u);
}

// ---------------- Fused: scores over full D + routing + aux ----------------
// 512 blocks x 32 tokens. Each block walks all 4 D-segments (W re-staged
// per segment from L2 via async DMA), accumulating the 18 dot products in
// registers, then routes its 32 tokens inline. No scores intermediate.
// LDS: W seg 36 KB + x double buffer 2 x 8 KB = 53,248 B -> 2 blocks/CU.
__global__ __launch_bounds__(256, 2) void fused_router_kernel(
    const float* __restrict__ x,
    const float* __restrict__ We,
    const float* __restrict__ Wg,
    float* __restrict__ out,
    unsigned int* __restrict__ gcounts)
{
    __shared__ float4 smem[WF4 + 2 * XB];   // 36,864 + 16,384 B
    __shared__ unsigned int lcnt[16];

    const int tid   = threadIdx.x;
    const int strip = blockIdx.x;           // 0..511, 32 tokens each

    const float4* __restrict__ x4  = reinterpret_cast<const float4*>(x);
    const float4* __restrict__ We4 = reinterpret_cast<const float4*>(We);
    const float4* __restrict__ Wg4 = reinterpret_cast<const float4*>(Wg);

    const int wave = tid >> 6;
    const int lane = tid & 63;
    const int l16  = lane & 15;
    const int g    = tid >> 4;              // 16-lane group id, 0..15

    // ---- prologue: DMA W segment 0 (9 instr/wave) + x chunk 0 ----
#pragma unroll
    for (int k = 0; k < 9; ++k) {
        const int idx = wave * 576 + k * 64 + lane;    // 0..2303
        const int e = idx >> 7;                        // 0..17
        const int d = idx & 127;
        const float4* gsrc = ((e < 16) ? (We4 + (size_t)e * D4)
                                       : (Wg4 + (size_t)(e - 16) * D4)) + d;
        ASYNC_CP16(gsrc, smem + wave * 576 + k * 64);
    }
#pragma unroll
    for (int i = 0; i < 2; ++i) {
        const int t = wave * 8 + i * 4 + (lane >> 4);
        const float4* gsrc = x4 + (size_t)(strip * 32 + t) * D4 + (lane & 15);
        ASYNC_CP16(gsrc, smem + WF4 + wave * 128 + i * 64);
    }
    if (tid < 16) lcnt[tid] = 0u;
    __syncthreads();   // vmcnt(0) drain: W seg 0 + x chunk 0 resident

    float a0[18], a1[18];
#pragma unroll
    for (int e = 0; e < 18; ++e) { a0[e] = 0.f; a1[e] = 0.f; }

    for (int cc = 0; cc < NCC; ++cc) {
        const int cur = cc & 1;
        const int ch  = cc & 7;

        // Issue next chunk's x DMA first -- in flight across the compute.
        if (cc + 1 < NCC) {
#pragma unroll
            for (int i = 0; i < 2; ++i) {
                const int t = wave * 8 + i * 4 + (lane >> 4);
                const float4* gsrc = x4 + (size_t)(strip * 32 + t) * D4
                                     + (cc + 1) * 16 + (lane & 15);
                ASYNC_CP16(gsrc, smem + WF4 + (cur ^ 1) * XB + wave * 128 + i * 64);
            }
        }

        // Compute on current buffer (LDS only).
        const float4* xcur = smem + WF4 + cur * XB + g * 32 + l16;
        const float4 xv0 = xcur[0];
        const float4 xv1 = xcur[16];
#pragma unroll
        for (int e = 0; e < 18; ++e) {
            const float4 w = smem[e * 128 + ch * 16 + l16];  // broadcast
            a0[e] += DOT4(w, xv0);
            a1[e] += DOT4(w, xv1);
        }

        __syncthreads();   // drains next-chunk DMA; protects buffer swap

        // Segment boundary: re-stage W for the next segment (x chunk for
        // the new segment is already in flight from the prefetch above).
        if (ch == 7 && cc + 1 < NCC) {
            const int seg = (cc + 1) >> 3;
#pragma unroll
            for (int k = 0; k < 9; ++k) {
                const int idx = wave * 576 + k * 64 + lane;
                const int e = idx >> 7;
                const int d = idx & 127;
                const float4* gsrc = ((e < 16) ? (We4 + (size_t)e * D4)
                                               : (Wg4 + (size_t)(e - 16) * D4))
                                     + seg * 128 + d;
                ASYNC_CP16(gsrc, smem + wave * 576 + k * 64);
            }
            __syncthreads();   // drain: next W seg (+ prefetched x) resident
        }
    }

    // ---- reduce 36 sums across each 16-lane group (pure VALU) ----
#pragma unroll
    for (int e = 0; e < 18; ++e) {
        a0[e] = row_reduce16(a0[e]);
        a1[e] = row_reduce16(a1[e]);
    }

    // ---- routing: lane 0 of each group handles its 2 tokens ----
    if (l16 == 0) {
        const int tok = strip * 32 + g * 2;
        route_one(a0, tok,     out, lcnt);
        route_one(a1, tok + 1, out, lcnt);
    }

    __syncthreads();
    if (tid < 16) {
        const unsigned int c = lcnt[tid];
        if (c) atomicAdd(&gcounts[tid], c);
    }
    __syncthreads();

    // Last-block ticket: aux loss. Reference bincount counts the 2 zero-pad
    // indices per token -> expert 0 gets +2*NTOK; total = 6*NTOK.
    if (tid == 0) {
        __threadfence();
        const unsigned int t = atomicAdd(&gcounts[16], 1u);
        if (t == gridDim.x - 1) {
            const float total = 6.0f * (float)NTOK;
            const float uni = 1.0f / 16.0f;
            float aux = 0.f;
            for (int e = 0; e < 16; ++e) {
                float c = (float)atomicAdd(&gcounts[e], 0u)
                          + (e == 0 ? 2.0f * (float)NTOK : 0.0f);
                aux += uni * (logf(uni) - logf(c / total));
            }
            out[2 * NW6] = aux * 0.01f;
        }
    }
}

extern "C" void kernel_launch(void* const* d_in, const int* in_sizes, int n_in,
                              void* d_out, int out_size, void* d_ws, size_t ws_size,
                              hipStream_t stream)
{
    const float* x  = (const float*)d_in[0];   // (4,4096,2048)
    const float* We = (const float*)d_in[1];   // (16,2048)
    const float* Wg = (const float*)d_in[2];   // (2,2048)
    float* out = (float*)d_out;

    unsigned int* counts = (unsigned int*)d_ws;

    hipMemsetAsync(counts, 0, 17 * sizeof(unsigned int), stream);

    // Single fused kernel: 512 token-strips of 32 tokens, full-D walk.
    fused_router_kernel<<<dim3(512), 256, 0, stream>>>(x, We, Wg, out, counts);
}

// Round 5
// 233.409 us; speedup vs baseline: 1.0107x; 1.0107x over previous
//
#include <hip/hip_runtime.h>
#include <math.h>
#include <stdint.h>

#define NTOK  16384
#define NW6   (NTOK * 6)
#define D4    512              // float4 per full 2048-dim row
#define WF4   2304             // 18 rows x 128 float4 per D-segment (36,864 B)
#define XWAVE 512              // 4 bufs x 128 float4 per wave (8 KB/wave)
#define NCC   32               // 64-dim chunks across full D (4 seg x 8)

#define DOT4(a, b) ((a).x*(b).x + (a).y*(b).y + (a).z*(b).z + (a).w*(b).w)

// Async global->LDS DMA, 16 B per lane. LDS dest = wave-uniform base +
// lane*16 (contiguous); global src is per-lane. No destination VGPRs.
#define ASYNC_CP16(gsrc, ldst)                                              \
    __builtin_amdgcn_global_load_lds(                                       \
        (const __attribute__((address_space(1))) void*)(gsrc),              \
        (__attribute__((address_space(3))) void*)(ldst), 16, 0, 0)

// Counted vmem wait (T4): never drain to 0 in the main loop. "memory"
// clobber stops the compiler hoisting the dependent ds_reads above it.
template <int N>
__device__ __forceinline__ void waitv() {
    asm volatile("s_waitcnt vmcnt(%0)" :: "i"(N) : "memory");
}

// DPP row_shl sum-tree: lane i adds lane i+N (out-of-range -> 0). After 4
// steps lane 0 of each 16-lane row holds the full row sum. (Verified.)
template <int CTRL>
__device__ __forceinline__ float dpp_add(float v) {
    int moved = __builtin_amdgcn_update_dpp(0, __float_as_int(v),
                                            CTRL, 0xF, 0xF, true);
    return v + __int_as_float(moved);
}
__device__ __forceinline__ float row_reduce16(float v) {
    v = dpp_add<0x108>(v);   // row_shl:8
    v = dpp_add<0x104>(v);   // row_shl:4
    v = dpp_add<0x102>(v);   // row_shl:2
    v = dpp_add<0x101>(v);   // row_shl:1
    return v;
}

// Routing math for one token given its 18 full scores (math identical to
// reference `_router`; verified passing in round 1).
__device__ __forceinline__ void route_one(const float* __restrict__ s,
                                          int tok,
                                          float* __restrict__ out,
                                          unsigned int* __restrict__ lcnt)
{
    const float g0 = 1.f / (1.f + expf(-s[16]));
    const float g1 = 1.f / (1.f + expf(-s[17]));

    // --- Group A: experts 0..7, top-1 of softmax ---
    int aidx = 0; float amax = s[0];
#pragma unroll
    for (int i = 1; i < 8; ++i)
        if (s[i] > amax) { amax = s[i]; aidx = i; }
    float asum = 0.f;
#pragma unroll
    for (int i = 0; i < 8; ++i) asum += expf(s[i] - amax);
    const float a_best = 1.f / asum;

    // --- Group B: experts 8..11, top-1, gated by g0 ---
    int bidx = 0; float bmax = s[8];
#pragma unroll
    for (int i = 1; i < 4; ++i)
        if (s[8 + i] > bmax) { bmax = s[8 + i]; bidx = i; }
    float bsum = 0.f;
#pragma unroll
    for (int i = 0; i < 4; ++i) bsum += expf(s[8 + i] - bmax);
    const float b_w = (g0 > 0.15f) ? ((1.f / bsum) * g0) : 0.f;

    // --- Group C: experts 12..15, top-2 of softmax, gated by g1 ---
    int c1 = 0; float cmax = s[12];
#pragma unroll
    for (int i = 1; i < 4; ++i)
        if (s[12 + i] > cmax) { cmax = s[12 + i]; c1 = i; }
    float csum = 0.f;
#pragma unroll
    for (int i = 0; i < 4; ++i) csum += expf(s[12 + i] - cmax);
    int c2 = -1; float c2v = -1e30f;
#pragma unroll
    for (int i = 0; i < 4; ++i)
        if (i != c1 && s[12 + i] > c2v) { c2v = s[12 + i]; c2 = i; }
    const float cg   = (g1 > 0.15f) ? g1 : 0.f;
    const float c_w1 = (1.f / csum) * cg;
    const float c_w2 = (expf(c2v - cmax) / csum) * cg;

    // --- normalize and write ---
    const float inv = 1.f / (a_best + b_w + c_w1 + c_w2 + 1e-8f);
    float2* ow = reinterpret_cast<float2*>(out + (size_t)tok * 6);
    ow[0] = make_float2(a_best * inv, b_w * inv);
    ow[1] = make_float2(c_w1 * inv, c_w2 * inv);
    ow[2] = make_float2(0.f, 0.f);
    float2* oi = reinterpret_cast<float2*>(out + NW6 + (size_t)tok * 6);
    oi[0] = make_float2((float)aidx, (float)(8 + bidx));
    oi[1] = make_float2((float)(12 + c1), (float)(12 + c2));
    oi[2] = make_float2(0.f, 0.f);

    atomicAdd(&lcnt[aidx], 1u);
    atomicAdd(&lcnt[8 + bidx], 1u);
    atomicAdd(&lcnt[12 + c1], 1u);
    atomicAdd(&lcnt[12 + c2], 1u);
}

// ---------------- Fused: scores over full D + routing + aux ----------------
// 512 blocks x 32 tokens, full-D walk. Key structure: each wave DMAs x only
// into its OWN 4-deep LDS ring and reads only its own ring -> the x pipeline
// runs with per-wave counted vmcnt (steady state vmcnt(6), 3 chunks in
// flight) and ZERO block barriers. W (block-shared, 36 KB/segment) is
// re-staged at the 3 segment boundaries with raw s_barrier pairs.
// LDS: 36,864 (W) + 4 waves x 8,192 (x rings) = 69,696 B -> 2 blocks/CU.
__global__ __launch_bounds__(256, 2) void fused_router_kernel(
    const float* __restrict__ x,
    const float* __restrict__ We,
    const float* __restrict__ Wg,
    float* __restrict__ out,
    unsigned int* __restrict__ gcounts)
{
    __shared__ float4 smem[WF4 + 4 * XWAVE];   // 36,864 + 32,768 B
    __shared__ unsigned int lcnt[16];

    const int tid   = threadIdx.x;
    const int strip = blockIdx.x;           // 0..511, 32 tokens each

    const float4* __restrict__ x4  = reinterpret_cast<const float4*>(x);
    const float4* __restrict__ We4 = reinterpret_cast<const float4*>(We);
    const float4* __restrict__ Wg4 = reinterpret_cast<const float4*>(Wg);

    const int wave  = tid >> 6;
    const int lane  = tid & 63;
    const int l16   = lane & 15;
    const int gl    = lane >> 4;            // 16-lane group within wave, 0..3
    const int xbase = WF4 + wave * XWAVE;   // this wave's x ring (float4 idx)

    // Stage the 18x512-dim W segment `seg` into LDS (9 DMA instr/wave).
    auto stage_W = [&](int seg) {
#pragma unroll
        for (int k = 0; k < 9; ++k) {
            const int idx = wave * 576 + k * 64 + lane;    // 0..2303
            const int e = idx >> 7;                        // 0..17
            const int d = idx & 127;
            const float4* gsrc = ((e < 16) ? (We4 + (size_t)e * D4)
                                           : (Wg4 + (size_t)(e - 16) * D4))
                                 + seg * 128 + d;
            ASYNC_CP16(gsrc, smem + wave * 576 + k * 64);
        }
    };

    // Issue this wave's 8 tokens x 64 dims of chunk cc into ring slot cc&3
    // (2 DMA instr). Token t lands at float4 offset t*16 within the slot.
    auto issue_x = [&](int cc) {
        const int buf = cc & 3;
#pragma unroll
        for (int i = 0; i < 2; ++i) {
            const int t = wave * 8 + i * 4 + (lane >> 4);
            const float4* gsrc = x4 + (size_t)(strip * 32 + t) * D4
                                 + cc * 16 + l16;
            ASYNC_CP16(gsrc, smem + xbase + buf * 128 + i * 64);
        }
    };

    float a0[18], a1[18];
#pragma unroll
    for (int e = 0; e < 18; ++e) { a0[e] = 0.f; a1[e] = 0.f; }

    // Compute chunk cc from ring slot cc&3 against W column cc&7.
    auto compute = [&](int cc) {
        const int ch  = cc & 7;
        const int buf = cc & 3;
        const float4* xcur = smem + xbase + buf * 128 + gl * 32 + l16;
        const float4 xv0 = xcur[0];     // token 2g
        const float4 xv1 = xcur[16];    // token 2g+1
#pragma unroll
        for (int e = 0; e < 18; ++e) {
            const float4 w = smem[e * 128 + ch * 16 + l16];  // broadcast
            a0[e] += DOT4(w, xv0);
            a1[e] += DOT4(w, xv1);
        }
    };

    // ---- prologue: W seg 0 + x chunks 0..2; full drain ----
    stage_W(0);
    issue_x(0); issue_x(1); issue_x(2);
    if (tid < 16) lcnt[tid] = 0u;
    __syncthreads();                    // vmcnt(0) drain: W0 + x0..2 resident

    for (int seg = 0; seg < 4; ++seg) {
        if (seg) {
            // All waves done READING old W (their ds_reads were consumed
            // before reaching here) -> safe to overwrite after barrier.
            __builtin_amdgcn_s_barrier();
            stage_W(seg);
            waitv<0>();                 // own W loads + x prefetches landed
            __builtin_amdgcn_s_barrier();  // everyone's W slice resident
        }
        const int lim = (seg == 3) ? 5 : 8;
        for (int i = 0; i < lim; ++i) {
            const int cc = seg * 8 + i;     // cc <= 28 here
            issue_x(cc + 3);                // 3 chunks ahead, 6 loads in flight
            waitv<6>();                     // chunk cc resident
            compute(cc);
        }
    }
    // ---- tail: drain the last 3 chunks with counted waits ----
    waitv<4>(); compute(29);
    waitv<2>(); compute(30);
    waitv<0>(); compute(31);

    // ---- reduce 36 sums across each 16-lane group (pure VALU) ----
#pragma unroll
    for (int e = 0; e < 18; ++e) {
        a0[e] = row_reduce16(a0[e]);
        a1[e] = row_reduce16(a1[e]);
    }

    // ---- routing: lane 0 of each group handles its 2 tokens ----
    const int g = tid >> 4;             // block-level group id, 0..15
    if (l16 == 0) {
        const int tok = strip * 32 + g * 2;
        route_one(a0, tok,     out, lcnt);
        route_one(a1, tok + 1, out, lcnt);
    }

    __syncthreads();
    if (tid < 16) {
        const unsigned int c = lcnt[tid];
        if (c) atomicAdd(&gcounts[tid], c);
    }
    __syncthreads();

    // Last-block ticket: aux loss. Reference bincount counts the 2 zero-pad
    // indices per token -> expert 0 gets +2*NTOK; total = 6*NTOK.
    if (tid == 0) {
        __threadfence();
        const unsigned int t = atomicAdd(&gcounts[16], 1u);
        if (t == gridDim.x - 1) {
            const float total = 6.0f * (float)NTOK;
            const float uni = 1.0f / 16.0f;
            float aux = 0.f;
            for (int e = 0; e < 16; ++e) {
                float c = (float)atomicAdd(&gcounts[e], 0u)
                          + (e == 0 ? 2.0f * (float)NTOK : 0.0f);
                aux += uni * (logf(uni) - logf(c / total));
            }
            out[2 * NW6] = aux * 0.01f;
        }
    }
}

extern "C" void kernel_launch(void* const* d_in, const int* in_sizes, int n_in,
                              void* d_out, int out_size, void* d_ws, size_t ws_size,
                              hipStream_t stream)
{
    const float* x  = (const float*)d_in[0];   // (4,4096,2048)
    const float* We = (const float*)d_in[1];   // (16,2048)
    const float* Wg = (const float*)d_in[2];   // (2,2048)
    float* out = (float*)d_out;

    unsigned int* counts = (unsigned int*)d_ws;

    hipMemsetAsync(counts, 0, 17 * sizeof(unsigned int), stream);

    // Single fused kernel: 512 token-strips of 32 tokens, full-D walk.
    fused_router_kernel<<<dim3(512), 256, 0, stream>>>(x, We, Wg, out, counts);
}